// Round 5
// baseline (187.491 us; speedup 1.0000x reference)
//
#include <hip/hip_runtime.h>

// ISTA T=5, LAM=0.1, B=L=4096, K=128. Loop-invariant algebra:
//   u = corr(y - corr(y,h), rev(h));  x = 5*soft_thresh(s*u, LAM).
// R5: FUSED composite filter. For interior columns (i in [63, 4032)):
//   u[i] = sum_d c[d]*y_ext[i+d],  c[d] = h[64-d]*1[-63<=d<=64] - ac[d-1],
//   ac[t] = sum_n h[n]h[n+t]  (width 255; exact where conv1's SAME-pad
//   clipping is invisible). Edge columns [0,64) and [4032,4096) are
//   recomputed exactly in fp32 by a fixup kernel (stream-ordered overwrite).
// Kernel 1 precomputes c and the 9 Toeplitz A-fragments into d_ws, removing
// the per-block scattered A-build. Main kernel: stage y -> ONE barrier ->
// 9 MFMA per 16x16 tile -> closed-form epilogue.

typedef __bf16 bf16;
typedef __bf16 bf16x4 __attribute__((ext_vector_type(4)));
typedef __bf16 bf16x8 __attribute__((ext_vector_type(8)));
typedef float f32x4 __attribute__((ext_vector_type(4)));

#define LC 512
#define PY 792   // bf16 row pitch: 396 dw, 396%32=12 -> conflict-free phases
#define LAM 0.1f

// ---------- kernel 1: composite filter + A-fragments -> ws ----------
__global__ __launch_bounds__(256) void ista_precomp(
    const float* __restrict__ h, bf16* __restrict__ wfrag) {
  __shared__ float hl[128];
  __shared__ float cf[288];  // c[d] at cf[d+128], d in [-128,160); 0 outside
  const int tid = threadIdx.x;
  if (tid < 128) hl[tid] = h[tid];
  cf[tid] = 0.f;
  if (tid < 32) cf[256 + tid] = 0.f;
  __syncthreads();
  {
    int d = tid - 127;           // [-127, 128] covers all nonzero c
    int lag = d - 1;
    float ac = 0.f;
    for (int n = 0; n < 128; ++n) {
      int m = n + lag;
      float hm = (m >= 0 && m < 128) ? hl[m] : 0.f;
      ac = fmaf(hl[n], hm, ac);
    }
    float cd = ((d >= -63 && d <= 64) ? hl[64 - d] : 0.f) - ac;
    cf[d + 128] = cd;
  }
  __syncthreads();
  // A[dd][lane]: A[m=li][k=quad*8+j] = c[-128 + dd*32 + k - li]
  for (int e = tid; e < 9 * 64; e += 256) {
    int dd = e >> 6, lane = e & 63, li = lane & 15, quad = lane >> 4;
    bf16x8 f;
#pragma unroll
    for (int j = 0; j < 8; ++j) {
      int d = -128 + dd * 32 + quad * 8 + j - li;  // [-143, 159]
      f[j] = (bf16)((d >= -128) ? cf[d + 128] : 0.f);
    }
    reinterpret_cast<bf16x8*>(wfrag)[e] = f;
  }
}

// ---------- kernel 2: main composite conv (interior-exact) ----------
__global__ __launch_bounds__(256, 4) void ista_main(
    const float* __restrict__ y, const float* __restrict__ step,
    const bf16* __restrict__ wfrag, float* __restrict__ out) {
  __shared__ __align__(16) bf16 ys[16 * PY];

  const int tid = threadIdx.x;
  const int lane = tid & 63;
  const int wave = tid >> 6;
  const int li = lane & 15;
  const int quad = lane >> 4;
  const int chunk0 = blockIdx.x * LC;
  const int b0 = blockIdx.y * 16;

  bf16x8 A[9];
#pragma unroll
  for (int dd = 0; dd < 9; ++dd)
    A[dd] = reinterpret_cast<const bf16x8*>(wfrag)[dd * 64 + lane];

  // stage y cols [chunk0-128, chunk0+656), zero-filled OOB
  {
    const int rr = tid >> 4;
    const int t = tid & 15;
    const float* yrow = y + (size_t)(b0 + rr) * 4096 + (chunk0 - 128);
    bf16* dst = ys + rr * PY;
    if (chunk0 >= 128 && chunk0 + 656 <= 4096) {
      for (int s4 = t; s4 < 196; s4 += 16) {
        float4 v = *reinterpret_cast<const float4*>(yrow + s4 * 4);
        bf16x4 bv;
        bv[0] = (bf16)v.x; bv[1] = (bf16)v.y;
        bv[2] = (bf16)v.z; bv[3] = (bf16)v.w;
        *reinterpret_cast<bf16x4*>(dst + s4 * 4) = bv;
      }
    } else {
      for (int s4 = t; s4 < 196; s4 += 16) {
        int l = chunk0 - 128 + s4 * 4;
        bf16x4 bv;
        bv[0] = (bf16)((l + 0 >= 0 && l + 0 < 4096) ? yrow[s4 * 4 + 0] : 0.f);
        bv[1] = (bf16)((l + 1 >= 0 && l + 1 < 4096) ? yrow[s4 * 4 + 1] : 0.f);
        bv[2] = (bf16)((l + 2 >= 0 && l + 2 < 4096) ? yrow[s4 * 4 + 2] : 0.f);
        bv[3] = (bf16)((l + 3 >= 0 && l + 3 < 4096) ? yrow[s4 * 4 + 3] : 0.f);
        *reinterpret_cast<bf16x4*>(dst + s4 * 4) = bv;
      }
    }
  }
  __syncthreads();

  const float s = step[0];
#pragma unroll
  for (int i = 0; i < 8; ++i) {
    const int i0 = 16 * (wave + 4 * i);
    const bf16* base = ys + li * PY + i0 + quad * 8;
    f32x4 acc = {0.f, 0.f, 0.f, 0.f};
#pragma unroll
    for (int dd = 0; dd < 9; ++dd) {
      bf16x8 bfrag = *reinterpret_cast<const bf16x8*>(base + dd * 32);
      acc = __builtin_amdgcn_mfma_f32_16x16x32_bf16(A[dd], bfrag, acc, 0, 0, 0);
    }
    float4 xv;
#pragma unroll
    for (int e = 0; e < 4; ++e) {
      float su = s * acc[e];
      float ax = fmaxf(fabsf(su) - LAM, 0.f);
      (&xv.x)[e] = copysignf(5.f * ax, su);
    }
    *reinterpret_cast<float4*>(
        out + (size_t)(b0 + li) * 4096 + chunk0 + i0 + quad * 4) = xv;
  }
}

// ---------- kernel 3: exact fp32 fixup of 64 edge cols per side ----------
__global__ __launch_bounds__(256) void ista_fixup(
    const float* __restrict__ y, const float* __restrict__ h,
    const float* __restrict__ step, float* __restrict__ out) {
  __shared__ float hl[128];
  __shared__ float yl[4][192];
  __shared__ float rl[4][128];
  const int tid = threadIdx.x;
  const int lane = tid & 63;
  const int w = tid >> 6;
  if (tid < 128) hl[tid] = h[tid];
  const int g = blockIdx.x * 4 + w;       // row-edge id
  const int row = g >> 1;
  const int side = g & 1;
  const float* yr = y + (size_t)row * 4096;
  const int ybase = side ? 3904 : 0;
  for (int k = lane; k < 192; k += 64) yl[w][k] = yr[ybase + k];
  __syncthreads();
  const int rbase = side ? 3968 : 0;
#pragma unroll
  for (int half = 0; half < 2; ++half) {
    int ip = rbase + lane + 64 * half;    // r index
    float acc = 0.f;
    for (int j = 0; j < 128; ++j) {
      int yc = ip + j - 63;
      float yv = (yc >= 0 && yc < 4096) ? yl[w][yc - ybase] : 0.f;
      acc = fmaf(hl[j], yv, acc);
    }
    rl[w][ip - rbase] = yl[w][ip - ybase] - acc;
  }
  __syncthreads();
  const int i = (side ? 4032 : 0) + lane;
  float u = 0.f;
  for (int n = 0; n < 128; ++n) {
    int ir = i + 64 - n;                  // r_ext index
    float rv = (ir >= rbase && ir < rbase + 128 && ir < 4096)
                   ? rl[w][ir - rbase] : 0.f;
    u = fmaf(hl[n], rv, u);
  }
  float su = step[0] * u;
  float ax = fmaxf(fabsf(su) - LAM, 0.f);
  out[(size_t)row * 4096 + i] = copysignf(5.f * ax, su);
}

extern "C" void kernel_launch(void* const* d_in, const int* in_sizes, int n_in,
                              void* d_out, int out_size, void* d_ws,
                              size_t ws_size, hipStream_t stream) {
  const float* y = (const float*)d_in[0];
  const float* h = (const float*)d_in[1];
  const float* s = (const float*)d_in[2];
  float* out = (float*)d_out;
  bf16* wfrag = (bf16*)d_ws;  // 9*64*16 B = 9216 B
  ista_precomp<<<dim3(1), dim3(256), 0, stream>>>(h, wfrag);
  ista_main<<<dim3(4096 / LC, 256), dim3(256), 0, stream>>>(y, s, wfrag, out);
  ista_fixup<<<dim3(4096 * 2 / 4), dim3(256), 0, stream>>>(y, h, s, out);
}

// Round 6
// 158.624 us; speedup vs baseline: 1.1820x; 1.1820x over previous
//
#include <hip/hip_runtime.h>

// ISTA T=5, LAM=0.1, B=L=4096, K=128. Loop-invariant algebra:
//   u = corr(y - corr(y,h), rev(h));  x = 5*soft_thresh(s*u, LAM).
// Composite filter (R5): u[i] = sum_d c[d]*y[i+d], c[d] = h-term - autocorr,
// exact for i in [63,4032); edges ([0,64) and [4032,4096)) recomputed in
// fp32 by a folded-in fixup phase (main path skips those stores).
// R6: ONE launch, persistent 1024 blocks (4/CU, one generation), each block
// pipelines 4 consecutive 256-col chunks of one 16-row group through
// double-buffered LDS: issue loads t+1 -> MFMA chunk t -> commit t+1 -> barrier.

typedef __bf16 bf16;
typedef __bf16 bf16x4 __attribute__((ext_vector_type(4)));
typedef __bf16 bf16x8 __attribute__((ext_vector_type(8)));
typedef float f32x4 __attribute__((ext_vector_type(4)));

#define LC 256
#define HALO_L 128
#define SPAN 544          // LC + 288 filter span
#define PY 552            // bf16 row pitch: 276 dw, 276%32=20 -> 2/bank max
#define NT 4              // chunks per block
#define LAM 0.1f

__global__ __launch_bounds__(256, 4) void ista_all(
    const float* __restrict__ y, const float* __restrict__ h,
    const float* __restrict__ step, float* __restrict__ out) {
  __shared__ __align__(16) bf16 ys[2][16 * PY];   // double-buffered y stage
  __shared__ float hl[128];
  __shared__ float cf[304];   // c[d] at cf[d+144], d in [-144,160)

  const int tid = threadIdx.x;
  const int lane = tid & 63;
  const int wave = tid >> 6;
  const int li = lane & 15;   // C column b AND A row i
  const int quad = lane >> 4;
  const int p = blockIdx.x;
  const int bg = p >> 2;              // 16-row batch group
  const int c_base = (p & 3) * 4;     // first chunk of this block
  const int b0 = bg * 16;
  const int rr = tid >> 4;            // staging row 0..15
  const int tt = tid & 15;

  // ---- h -> LDS, zero cf ----
  if (tid < 128) hl[tid] = h[tid];
  if (tid < 152) { cf[tid] = 0.f; cf[tid + 152] = 0.f; }
  __syncthreads();

  float4 ld[9];
  auto issue = [&](int c, float4* l) {
    const int c0 = c * LC;
    const float* yrow = y + (size_t)(b0 + rr) * 4096 + (c0 - HALO_L);
    if (c >= 1 && c <= 14) {
#pragma unroll
      for (int k = 0; k < 9; ++k)
        if (k < 8 || tt < 8)
          l[k] = *reinterpret_cast<const float4*>(yrow + (tt + 16 * k) * 4);
    } else {
#pragma unroll
      for (int k = 0; k < 9; ++k)
        if (k < 8 || tt < 8) {
          int base = c0 - HALO_L + (tt + 16 * k) * 4;
          float4 v;
          v.x = ((unsigned)(base + 0) < 4096u) ? yrow[(tt + 16 * k) * 4 + 0] : 0.f;
          v.y = ((unsigned)(base + 1) < 4096u) ? yrow[(tt + 16 * k) * 4 + 1] : 0.f;
          v.z = ((unsigned)(base + 2) < 4096u) ? yrow[(tt + 16 * k) * 4 + 2] : 0.f;
          v.w = ((unsigned)(base + 3) < 4096u) ? yrow[(tt + 16 * k) * 4 + 3] : 0.f;
          l[k] = v;
        }
    }
  };
  auto commit = [&](int buf, const float4* l) {
    bf16* dst = ys[buf] + rr * PY;
#pragma unroll
    for (int k = 0; k < 9; ++k)
      if (k < 8 || tt < 8) {
        float4 v = l[k];
        bf16x4 bv;
        bv[0] = (bf16)v.x; bv[1] = (bf16)v.y;
        bv[2] = (bf16)v.z; bv[3] = (bf16)v.w;
        *reinterpret_cast<bf16x4*>(dst + (tt + 16 * k) * 4) = bv;
      }
  };

  // ---- prologue: loads for chunk 0 in flight while building c and A ----
  issue(c_base, ld);
  {
    int d = tid - 127;         // [-127,128] covers all nonzero c[d]
    int lag = d - 1;
    float ac = 0.f;
    for (int n = 0; n < 128; ++n) {
      int m = n + lag;
      float hm = ((unsigned)m < 128u) ? hl[m] : 0.f;
      ac = fmaf(hl[n], hm, ac);
    }
    cf[d + 144] = ((d >= -63 && d <= 64) ? hl[64 - d] : 0.f) - ac;
  }
  __syncthreads();

  bf16x8 A[9];   // A[m=li][k=quad*8+j] = c[-128 + dd*32 + k - li]
#pragma unroll
  for (int dd = 0; dd < 9; ++dd) {
    bf16x8 a;
#pragma unroll
    for (int j = 0; j < 8; ++j) {
      int d = -128 + dd * 32 + quad * 8 + j - li;
      a[j] = (bf16)cf[d + 144];
    }
    A[dd] = a;
  }

  commit(0, ld);
  __syncthreads();

  // ---- pipelined main loop over NT chunks ----
  const float s = step[0];
  for (int it = 0; it < NT; ++it) {
    const int c = c_base + it;
    const int c0 = c * LC;
    if (it + 1 < NT) issue(c + 1, ld);

    const bf16* brow = ys[it & 1] + li * PY;
#pragma unroll
    for (int i = 0; i < 4; ++i) {
      const int i0 = 16 * (wave + 4 * i);
      const bf16* base = brow + i0 + quad * 8;
      f32x4 acc = {0.f, 0.f, 0.f, 0.f};
#pragma unroll
      for (int dd = 0; dd < 9; ++dd) {
        bf16x8 bfrag = *reinterpret_cast<const bf16x8*>(base + dd * 32);
        acc = __builtin_amdgcn_mfma_f32_16x16x32_bf16(A[dd], bfrag, acc, 0, 0, 0);
      }
      // edge cols are produced by the fixup phase instead
      bool skip = (c == 0 && i0 < 64) || (c == 15 && i0 >= 192);
      if (!skip) {
        float4 xv;
#pragma unroll
        for (int e = 0; e < 4; ++e) {
          float su = s * acc[e];
          float ax = fmaxf(fabsf(su) - LAM, 0.f);
          (&xv.x)[e] = copysignf(5.f * ax, su);
        }
        *reinterpret_cast<float4*>(
            out + (size_t)(b0 + li) * 4096 + c0 + i0 + quad * 4) = xv;
      }
    }

    if (it + 1 < NT) commit((it + 1) & 1, ld);
    __syncthreads();
  }

  // ---- fixup phase: 8 row-sides per block, 2 per wave, exact fp32 ----
  float* scr = reinterpret_cast<float*>(&ys[0][0]) + wave * 320;
  float* yl = scr;         // 192 floats
  float* rl = scr + 192;   // 128 floats
#pragma unroll
  for (int rep = 0; rep < 2; ++rep) {
    const int sid = p * 8 + wave * 2 + rep;
    const int row = sid >> 1;
    const int side = sid & 1;
    const float* yr = y + (size_t)row * 4096;
    const int ybase = side ? 3904 : 0;
    for (int k = lane; k < 192; k += 64) yl[k] = yr[ybase + k];
    __syncthreads();
    const int rbase = side ? 3968 : 0;
#pragma unroll
    for (int half = 0; half < 2; ++half) {
      int ip = rbase + lane + 64 * half;
      float acc = 0.f;
      for (int j = 0; j < 128; ++j) {
        int yc = ip + j - 63;
        float yv = ((unsigned)yc < 4096u) ? yl[yc - ybase] : 0.f;
        acc = fmaf(hl[j], yv, acc);
      }
      rl[ip - rbase] = yl[ip - ybase] - acc;
    }
    __syncthreads();
    const int i = (side ? 4032 : 0) + lane;
    float u = 0.f;
    for (int n = 0; n < 128; ++n) {
      int ir = i + 64 - n;
      float rv = (ir >= rbase && ir < rbase + 128 && ir < 4096)
                     ? rl[ir - rbase] : 0.f;
      u = fmaf(hl[n], rv, u);
    }
    float su = s * u;
    float ax = fmaxf(fabsf(su) - LAM, 0.f);
    out[(size_t)row * 4096 + i] = copysignf(5.f * ax, su);
    __syncthreads();
  }
}

extern "C" void kernel_launch(void* const* d_in, const int* in_sizes, int n_in,
                              void* d_out, int out_size, void* d_ws,
                              size_t ws_size, hipStream_t stream) {
  const float* y = (const float*)d_in[0];
  const float* h = (const float*)d_in[1];
  const float* s = (const float*)d_in[2];
  float* out = (float*)d_out;
  ista_all<<<dim3(1024), dim3(256), 0, stream>>>(y, h, s, out);
}